// Round 8
// baseline (191.422 us; speedup 1.0000x reference)
//
#include <hip/hip_runtime.h>
#include <math.h>

#define NB 16
#define IMH 288
#define IMW 384
#define NPIX (IMH*IMW)
#define TPB 256
#define PPT 8
#define BPB (NPIX/(TPB*PPT))   // 54 blocks per batch
#define NBLK (NB*BPB)          // 864
#define NITER 5

typedef float v2f __attribute__((ext_vector_type(2)));

// ws doubles: pose[2][NB][12] | posefin[NB][12] | acc[NITER][NB][27]; then ints cnt[NB+1]
#define POSE_OFF 0
#define PFIN_OFF (2*NB*12)
#define ACC_OFF  (2*NB*12 + NB*12)
#define WS_DOUBLES (ACC_OFF + NITER*NB*27)

__device__ __forceinline__ v2f sp2(float x){ v2f r; r[0]=x; r[1]=x; return r; }
__device__ __forceinline__ v2f pkfma(v2f a, float b, v2f c){ return __builtin_elementwise_fma(a, sp2(b), c); }

// Register-resident f64 LM update: fully unrolled, static indices only.
__device__ __forceinline__ void solve_update(const double* acc, const double* pin,
                                             double* Ro, double* to) {
    double A[6][6], rhs[6], inv[6];
    {
        int k = 0;
        #pragma unroll
        for (int f = 0; f < 6; f++)
            #pragma unroll 6
            for (int g = f; g < 6; g++) {
                double v = acc[k];
                A[f][g] = v; A[g][f] = v; k++;
            }
    }
    #pragma unroll
    for (int f = 0; f < 6; f++) rhs[f] = -acc[21 + f];

    double tr = A[0][0]+A[1][1]+A[2][2]+A[3][3]+A[4][4]+A[5][5];
    double damp = 1e-4 * tr / 6.0 + 1e-6;
    #pragma unroll
    for (int f = 0; f < 6; f++) A[f][f] += damp;

    #pragma unroll
    for (int j = 0; j < 6; j++) {
        double s = A[j][j];
        #pragma unroll 6
        for (int m = 0; m < j; m++) s -= A[j][m]*A[j][m];
        double dd = sqrt(fmax(s, 1e-30));
        A[j][j] = dd;
        inv[j] = 1.0 / dd;
        #pragma unroll 6
        for (int i = j + 1; i < 6; i++) {
            double s2 = A[i][j];
            #pragma unroll 6
            for (int m = 0; m < j; m++) s2 -= A[i][m]*A[j][m];
            A[i][j] = s2 * inv[j];
        }
    }
    #pragma unroll
    for (int i = 0; i < 6; i++) {
        double s = rhs[i];
        #pragma unroll 6
        for (int m = 0; m < i; m++) s -= A[i][m]*rhs[m];
        rhs[i] = s * inv[i];
    }
    #pragma unroll
    for (int i = 5; i >= 0; i--) {
        double s = rhs[i];
        #pragma unroll 6
        for (int m = i + 1; m < 6; m++) s -= A[m][i]*rhs[m];
        rhs[i] = s * inv[i];
    }

    to[0] = pin[9]  + rhs[0];
    to[1] = pin[10] + rhs[1];
    to[2] = pin[11] + rhs[2];

    double wx = rhs[3], wy = rhs[4], wz = rhs[5];
    double th = fmax(sqrt(wx*wx + wy*wy + wz*wz), 1e-8);
    double ith = 1.0 / th;
    double kx = wx*ith, ky = wy*ith, kz = wz*ith;
    float stf, ctf;
    sincosf((float)th, &stf, &ctf);       // f32 trig == reference semantics
    double st = (double)stf, ct = 1.0 - (double)ctf;
    double E[9];
    E[0] = 1.0 + ct*(kx*kx - 1.0);
    E[1] = -st*kz + ct*kx*ky;
    E[2] =  st*ky + ct*kx*kz;
    E[3] =  st*kz + ct*ky*kx;
    E[4] = 1.0 + ct*(ky*ky - 1.0);
    E[5] = -st*kx + ct*ky*kz;
    E[6] = -st*ky + ct*kz*kx;
    E[7] =  st*kx + ct*kz*ky;
    E[8] = 1.0 + ct*(kz*kz - 1.0);

    #pragma unroll
    for (int i = 0; i < 3; i++)
        #pragma unroll
        for (int j = 0; j < 3; j++)
            Ro[i*3+j] = E[i*3+0]*pin[0*3+j] + E[i*3+1]*pin[1*3+j] + E[i*3+2]*pin[2*3+j];
}

__device__ __forceinline__ void loss_dev(const double* ws, const float* pose, float* out) {
    int lane = threadIdx.x;
    double rot = 0.0, trans = 0.0;
    const double* pf0 = ws + PFIN_OFF;            // batch-0 predicted pose (broadcast read)
    if (lane < NB) {
        const float* P0 = pose;
        const float* Pb = pose + lane * 16;
        double R0t[9];
        #pragma unroll
        for (int i = 0; i < 3; i++)
            #pragma unroll
            for (int j = 0; j < 3; j++) R0t[i*3+j] = (double)P0[j*4+i];
        double t0i[3];
        #pragma unroll
        for (int i = 0; i < 3; i++)
            t0i[i] = -(R0t[i*3+0]*P0[0*4+3] + R0t[i*3+1]*P0[1*4+3] + R0t[i*3+2]*P0[2*4+3]);
        double Rg[9], tg[3];
        #pragma unroll
        for (int i = 0; i < 3; i++) {
            #pragma unroll
            for (int j = 0; j < 3; j++)
                Rg[i*3+j] = R0t[i*3+0]*Pb[0*4+j] + R0t[i*3+1]*Pb[1*4+j] + R0t[i*3+2]*Pb[2*4+j];
            tg[i] = R0t[i*3+0]*Pb[0*4+3] + R0t[i*3+1]*Pb[1*4+3] + R0t[i*3+2]*Pb[2*4+3] + t0i[i];
        }
        const double* pfb = ws + PFIN_OFF + lane * 12;
        double Rp0t[9];
        #pragma unroll
        for (int i = 0; i < 3; i++)
            #pragma unroll
            for (int j = 0; j < 3; j++) Rp0t[i*3+j] = pf0[j*3+i];
        double tp0i[3];
        #pragma unroll
        for (int i = 0; i < 3; i++)
            tp0i[i] = -(Rp0t[i*3+0]*pf0[9] + Rp0t[i*3+1]*pf0[10] + Rp0t[i*3+2]*pf0[11]);
        double Rr[9], trv[3];
        #pragma unroll
        for (int i = 0; i < 3; i++) {
            #pragma unroll
            for (int j = 0; j < 3; j++)
                Rr[i*3+j] = Rp0t[i*3+0]*pfb[0*3+j] + Rp0t[i*3+1]*pfb[1*3+j] + Rp0t[i*3+2]*pfb[2*3+j];
            trv[i] = Rp0t[i*3+0]*pfb[9] + Rp0t[i*3+1]*pfb[10] + Rp0t[i*3+2]*pfb[11] + tp0i[i];
        }
        double trace = 0.0;
        #pragma unroll
        for (int i = 0; i < 3; i++)
            trace += Rr[0*3+i]*Rg[0*3+i] + Rr[1*3+i]*Rg[1*3+i] + Rr[2*3+i]*Rg[2*3+i];
        double cosang = 0.5 * (trace - 1.0);
        cosang = fmin(fmax(cosang, -1.0 + 1e-7), 1.0 - 1e-7);
        rot = acos(cosang);
        double d0 = trv[0]-tg[0], d1 = trv[1]-tg[1], d2 = trv[2]-tg[2];
        trans = sqrt(d0*d0 + d1*d1 + d2*d2);
    }
    for (int off = 8; off > 0; off >>= 1) {
        rot   += __shfl_down(rot, off, 64);
        trans += __shfl_down(trans, off, 64);
    }
    if (lane == 0) {
        rot /= NB; trans /= NB;
        out[0] = (float)(rot + trans);
        out[1] = (float)rot;
        out[2] = (float)trans;
    }
}

__global__ void init_k(double* ws) {
    int i = threadIdx.x;
    for (int k = i; k < WS_DOUBLES; k += TPB) ws[k] = 0.0;
    int* cnt = (int*)(ws + WS_DOUBLES);
    for (int k = i; k < NB + 1; k += TPB) cnt[k] = 0;
    __syncthreads();
    if (i < NB) {
        double* p = ws + POSE_OFF + i * 12;   // parity buffer 0 = identity
        p[0] = 1.0; p[4] = 1.0; p[8] = 1.0;
    }
}

__global__ __launch_bounds__(TPB) void reduce_k(const float* __restrict__ x3d,
                                                const float* __restrict__ conf,
                                                const float* __restrict__ Kmat,
                                                const float* __restrict__ pose,
                                                float* __restrict__ out,
                                                double* __restrict__ ws,
                                                int it, int last) {
    const int b = blockIdx.x / BPB;
    const int chunk = blockIdx.x % BPB;
    const int tid = threadIdx.x;

    // ---- issue input loads FIRST (latency hides under prologue solve) ----
    const int ft = chunk * TPB + tid;              // [0, 13824)
    const float4* P4 = reinterpret_cast<const float4*>(x3d + (size_t)b * NPIX * 3) + (size_t)ft * 6;
    const float4* W4 = reinterpret_cast<const float4*>(conf + (size_t)b * NPIX) + (size_t)ft * 2;
    const float4 va = P4[0], vb = P4[1], vc = P4[2], vd = P4[3], ve = P4[4], vf = P4[5];
    const float4 w0 = W4[0], w1 = W4[1];

    __shared__ double sps[12];
    __shared__ double lred[4][27];

    float R[9], t[3];
    if (it == 0) {
        R[0]=1.f; R[1]=0.f; R[2]=0.f;
        R[3]=0.f; R[4]=1.f; R[5]=0.f;
        R[6]=0.f; R[7]=0.f; R[8]=1.f;
        t[0]=t[1]=t[2]=0.f;
    } else {
        if (tid < 64) {   // wave 0: redundant register-resident pose update
            double Rn[9], tn[3];
            solve_update(ws + ACC_OFF + ((size_t)(it-1) * NB + b) * 27,
                         ws + POSE_OFF + (size_t)((it-1) & 1) * NB * 12 + (size_t)b * 12,
                         Rn, tn);
            if (tid == 0) {
                #pragma unroll
                for (int i = 0; i < 9; i++) sps[i] = Rn[i];
                sps[9] = tn[0]; sps[10] = tn[1]; sps[11] = tn[2];
                if (chunk == 0) {   // publish pose state for next dispatch
                    double* pout = ws + POSE_OFF + (size_t)(it & 1) * NB * 12 + (size_t)b * 12;
                    #pragma unroll
                    for (int i = 0; i < 9; i++) pout[i] = Rn[i];
                    pout[9] = tn[0]; pout[10] = tn[1]; pout[11] = tn[2];
                }
            }
        }
        __syncthreads();
        #pragma unroll
        for (int i = 0; i < 9; i++) R[i] = (float)sps[i];
        t[0] = (float)sps[9]; t[1] = (float)sps[10]; t[2] = (float)sps[11];
    }

    const float fx = Kmat[b*9 + 0];
    const float fy = Kmat[b*9 + 4];
    const float cx = Kmat[b*9 + 2];
    const float cy = Kmat[b*9 + 5];
    const float delta = (float)(0.1 * sqrt(((double)(IMW*IMW - 1) + (double)(IMH*IMH - 1)) / 12.0));

    const int n0 = ft * PPT;
    const int v0 = n0 / IMW;                       // 8 points share one pixel row
    const float cyv  = cy - (float)v0;
    const float cxu0 = cx - (float)(n0 - v0 * IMW);

    float ppx[8] = { va.x, va.w, vb.z, vc.y, vd.x, vd.w, ve.z, vf.y };
    float ppy[8] = { va.y, vb.x, vb.w, vc.z, vd.y, ve.x, ve.w, vf.z };
    float ppz[8] = { va.z, vb.y, vc.x, vc.w, vd.z, ve.y, vf.x, vf.w };
    float pw[8]  = { w0.x, w0.y, w0.z, w0.w, w1.x, w1.y, w1.z, w1.w };

    // packed accumulators: A_f covers column-pairs of JTJ row f (g>=f pairs only)
    v2f A0[3], A1[3], A2[2], A3[2], A4, A5, AR[3];
    #pragma unroll
    for (int i = 0; i < 3; i++) { A0[i]=sp2(0.f); A1[i]=sp2(0.f); AR[i]=sp2(0.f); }
    A2[0]=sp2(0.f); A2[1]=sp2(0.f); A3[0]=sp2(0.f); A3[1]=sp2(0.f);
    A4=sp2(0.f); A5=sp2(0.f);

    #pragma unroll
    for (int g = 0; g < PPT; ++g) {
        float px = ppx[g], py = ppy[g], pz = ppz[g], w = pw[g];

        float Xx = fmaf(R[0], px, fmaf(R[1], py, fmaf(R[2], pz, t[0])));
        float Xy = fmaf(R[3], px, fmaf(R[4], py, fmaf(R[5], pz, t[1])));
        float Xz = fmaf(R[6], px, fmaf(R[7], py, fmaf(R[8], pz, t[2])));
        float z  = fmaxf(Xz, 0.01f);
        float iz = __builtin_amdgcn_rcpf(z);

        float Xxiz = Xx * iz, Xyiz = Xy * iz;
        float rx = fmaf(fx, Xxiz, cxu0 - (float)g);
        float ry = fmaf(fy, Xyiz, cyv);

        float wrx = w * rx, wry = w * ry;
        float q  = fmaf(wrx, wrx, wry * wry);
        float rs = __builtin_amdgcn_rsqf(fmaxf(q, 1e-16f));
        float rob2 = fminf(1.0f, delta * rs);
        float sq = w * __builtin_amdgcn_sqrtf(rob2);

        float sqiz = sq * iz;
        float a  = fx * sqiz;
        float c  = fy * sqiz;
        float bb = -a * Xxiz;
        float d  = -c * Xyiz;

        float j03 = bb * Xy;
        float j04 = fmaf(a, Xz, -bb * Xx);
        float j05 = -a * Xy;
        float j13 = fmaf(d, Xy, -c * Xz);
        float j14 = -d * Xx;
        float j15 = c * Xx;
        float rxs = sq * rx, rys = sq * ry;

        v2f j0p0; j0p0[0]=a;   j0p0[1]=0.f;
        v2f j0p1; j0p1[0]=bb;  j0p1[1]=j03;
        v2f j0p2; j0p2[0]=j04; j0p2[1]=j05;
        v2f j1p0; j1p0[0]=0.f; j1p0[1]=c;
        v2f j1p1; j1p1[0]=d;   j1p1[1]=j13;
        v2f j1p2; j1p2[0]=j14; j1p2[1]=j15;

        A0[0]=pkfma(j0p0,a,A0[0]);  A0[1]=pkfma(j0p1,a,A0[1]);  A0[2]=pkfma(j0p2,a,A0[2]);
        A1[0]=pkfma(j1p0,c,A1[0]);  A1[1]=pkfma(j1p1,c,A1[1]);  A1[2]=pkfma(j1p2,c,A1[2]);
        A2[0]=pkfma(j0p1,bb,A2[0]); A2[0]=pkfma(j1p1,d,A2[0]);
        A2[1]=pkfma(j0p2,bb,A2[1]); A2[1]=pkfma(j1p2,d,A2[1]);
        A3[0]=pkfma(j0p1,j03,A3[0]); A3[0]=pkfma(j1p1,j13,A3[0]);
        A3[1]=pkfma(j0p2,j03,A3[1]); A3[1]=pkfma(j1p2,j13,A3[1]);
        A4 = pkfma(j0p2,j04,A4);     A4 = pkfma(j1p2,j14,A4);
        A5 = pkfma(j0p2,j05,A5);     A5 = pkfma(j1p2,j15,A5);
        AR[0]=pkfma(j0p0,rxs,AR[0]); AR[0]=pkfma(j1p0,rys,AR[0]);
        AR[1]=pkfma(j0p1,rxs,AR[1]); AR[1]=pkfma(j1p1,rys,AR[1]);
        AR[2]=pkfma(j0p2,rxs,AR[2]); AR[2]=pkfma(j1p2,rys,AR[2]);
    }

    // extract the 27 unique values (triangle row-major, then JTr), pad to 32
    float cur[32];
    cur[0]=A0[0][0];  cur[1]=A0[0][1];  cur[2]=A0[1][0];  cur[3]=A0[1][1];  cur[4]=A0[2][0];  cur[5]=A0[2][1];
    cur[6]=A1[0][1];  cur[7]=A1[1][0];  cur[8]=A1[1][1];  cur[9]=A1[2][0];  cur[10]=A1[2][1];
    cur[11]=A2[0][0]; cur[12]=A2[0][1]; cur[13]=A2[1][0]; cur[14]=A2[1][1];
    cur[15]=A3[0][1]; cur[16]=A3[1][0]; cur[17]=A3[1][1];
    cur[18]=A4[0];    cur[19]=A4[1];
    cur[20]=A5[1];
    cur[21]=AR[0][0]; cur[22]=AR[0][1]; cur[23]=AR[1][0]; cur[24]=AR[1][1]; cur[25]=AR[2][0]; cur[26]=AR[2][1];
    cur[27]=0.f; cur[28]=0.f; cur[29]=0.f; cur[30]=0.f; cur[31]=0.f;

    // reduce-scatter butterfly: halve value-set per level; lane ends with value bitrev5(lane)
    const int lane = tid & 63;
    const int wave = tid >> 6;
    #pragma unroll
    for (int s = 0; s < 5; ++s) {
        const int m = 1 << s;
        const int h = 16 >> s;                  // half-count this stage
        const bool up = (lane & m) != 0;
        #pragma unroll
        for (int i = 0; i < h; ++i) {
            float keep = up ? cur[i + h] : cur[i];
            float send = up ? cur[i]     : cur[i + h];
            cur[i] = keep + __shfl_xor(send, m, 64);
        }
    }
    float tot = cur[0] + __shfl_xor(cur[0], 32, 64);
    int vidx = __brev((unsigned)lane) >> 27;    // bitrev5
    if (lane < 32 && vidx < 27) lred[wave][vidx] = (double)tot;
    __syncthreads();

    double* acc = ws + ACC_OFF + ((size_t)it * NB + b) * 27;
    if (tid < 27)
        atomicAdd(acc + tid, lred[0][tid] + lred[1][tid] + lred[2][tid] + lred[3][tid]);

    // ---- last iteration: fold final solve + loss into last-arriving blocks ----
    if (last) {
        __shared__ int s_doloss;
        __syncthreads();                        // drains this block's acc atomics
        if (tid == 0) {
            s_doloss = 0;
            int* cnt = (int*)(ws + WS_DOUBLES);
            int old = atomicAdd(&cnt[b], 1);
            if (old == BPB - 1) {               // batch-last block: final pose
                __threadfence();                // acquire all blocks' acc adds
                double Rn[9], tn[3];
                solve_update(acc, sps, Rn, tn); // sps holds P_4 from this block's prologue
                double* pf = ws + PFIN_OFF + (size_t)b * 12;
                #pragma unroll
                for (int i = 0; i < 9; i++) pf[i] = Rn[i];
                pf[9] = tn[0]; pf[10] = tn[1]; pf[11] = tn[2];
                __threadfence();                // release posefin
                int o2 = atomicAdd(&cnt[NB], 1);
                if (o2 == NB - 1) s_doloss = 1;
            }
        }
        __syncthreads();
        if (s_doloss && tid < 64) {
            __threadfence();                    // acquire all batches' posefin
            loss_dev(ws, pose, out);
        }
    }
}

extern "C" void kernel_launch(void* const* d_in, const int* in_sizes, int n_in,
                              void* d_out, int out_size, void* d_ws, size_t ws_size,
                              hipStream_t stream) {
    const float* x3d  = (const float*)d_in[0];
    const float* conf = (const float*)d_in[1];
    const float* Kmat = (const float*)d_in[2];
    const float* pose = (const float*)d_in[3];
    float* out = (float*)d_out;
    double* ws = (double*)d_ws;

    hipLaunchKernelGGL(init_k, dim3(1), dim3(TPB), 0, stream, ws);
    for (int it = 0; it < NITER; ++it) {
        hipLaunchKernelGGL(reduce_k, dim3(NBLK), dim3(TPB), 0, stream,
                           x3d, conf, Kmat, pose, out, ws, it, (it == NITER - 1) ? 1 : 0);
    }
}

// Round 9
// 109.136 us; speedup vs baseline: 1.7540x; 1.7540x over previous
//
#include <hip/hip_runtime.h>
#include <math.h>

#define NB 16
#define IMH 288
#define IMW 384
#define NPIX (IMH*IMW)
#define TPB 256
#define PPT 4                      // points per thread
#define BPB (NPIX/(TPB*PPT))       // 108 blocks per batch
#define NBLK (NB*BPB)              // 1728
#define NITER 5

// ws doubles layout: pose[2][NB][12] (R[9]+t[3], parity buffers) | acc[NITER][NB][27]
#define POSE_OFF 0
#define ACC_OFF (2*NB*12)
#define WS_DOUBLES (2*NB*12 + NITER*NB*27)

// Register-resident f64: pose_out = LM-update(pose_in, acc). Fully unrolled.
__device__ __forceinline__ void solve_update(const double* __restrict__ acc,
                                             const double* __restrict__ pin,
                                             double* __restrict__ Ro,
                                             double* __restrict__ to) {
    double A[6][6], rhs[6], inv[6];
    {
        int k = 0;
        #pragma unroll
        for (int f = 0; f < 6; f++) {
            #pragma unroll 6
            for (int g = f; g < 6; g++) {
                double v = acc[k];
                A[f][g] = v; A[g][f] = v; k++;
            }
        }
    }
    #pragma unroll
    for (int f = 0; f < 6; f++) rhs[f] = -acc[21 + f];

    double tr = A[0][0]+A[1][1]+A[2][2]+A[3][3]+A[4][4]+A[5][5];
    double damp = 1e-4 * tr / 6.0 + 1e-6;
    #pragma unroll
    for (int f = 0; f < 6; f++) A[f][f] += damp;

    #pragma unroll
    for (int j = 0; j < 6; j++) {
        double s = A[j][j];
        #pragma unroll 6
        for (int m = 0; m < j; m++) s -= A[j][m]*A[j][m];
        double dd = sqrt(fmax(s, 1e-30));
        A[j][j] = dd;
        inv[j] = 1.0 / dd;
        #pragma unroll 6
        for (int i = j + 1; i < 6; i++) {
            double s2 = A[i][j];
            #pragma unroll 6
            for (int m = 0; m < j; m++) s2 -= A[i][m]*A[j][m];
            A[i][j] = s2 * inv[j];
        }
    }
    #pragma unroll
    for (int i = 0; i < 6; i++) {
        double s = rhs[i];
        #pragma unroll 6
        for (int m = 0; m < i; m++) s -= A[i][m]*rhs[m];
        rhs[i] = s * inv[i];
    }
    #pragma unroll
    for (int i = 5; i >= 0; i--) {
        double s = rhs[i];
        #pragma unroll 6
        for (int m = i + 1; m < 6; m++) s -= A[m][i]*rhs[m];
        rhs[i] = s * inv[i];
    }

    to[0] = pin[9]  + rhs[0];
    to[1] = pin[10] + rhs[1];
    to[2] = pin[11] + rhs[2];

    double wx = rhs[3], wy = rhs[4], wz = rhs[5];
    double th = fmax(sqrt(wx*wx + wy*wy + wz*wz), 1e-8);
    double ith = 1.0 / th;
    double kx = wx*ith, ky = wy*ith, kz = wz*ith;
    float stf, ctf;
    sincosf((float)th, &stf, &ctf);      // f32 trig == reference semantics
    double st = (double)stf, ct = 1.0 - (double)ctf;
    double E[9];
    E[0] = 1.0 + ct*(kx*kx - 1.0);
    E[1] = -st*kz + ct*kx*ky;
    E[2] =  st*ky + ct*kx*kz;
    E[3] =  st*kz + ct*ky*kx;
    E[4] = 1.0 + ct*(ky*ky - 1.0);
    E[5] = -st*kx + ct*ky*kz;
    E[6] = -st*ky + ct*kz*kx;
    E[7] =  st*kx + ct*kz*ky;
    E[8] = 1.0 + ct*(kz*kz - 1.0);

    #pragma unroll
    for (int i = 0; i < 3; i++) {
        #pragma unroll
        for (int j = 0; j < 3; j++)
            Ro[i*3+j] = E[i*3+0]*pin[0*3+j] + E[i*3+1]*pin[1*3+j] + E[i*3+2]*pin[2*3+j];
    }
}

__global__ void init_k(double* ws) {
    int i = threadIdx.x;
    for (int k = i; k < WS_DOUBLES; k += TPB) ws[k] = 0.0;
    __syncthreads();
    if (i < NB) {
        double* p = ws + POSE_OFF + i * 12;   // parity buffer 0 = identity
        p[0] = 1.0; p[4] = 1.0; p[8] = 1.0;
    }
}

__global__ __launch_bounds__(TPB) void reduce_k(const float* __restrict__ x3d,
                                                const float* __restrict__ conf,
                                                const float* __restrict__ Kmat,
                                                double* __restrict__ ws, int it) {
    // batch = blockIdx % 16: XCD round-robin puts batch b's blocks on XCD b%8
    // -> 2 batches (3.5 MB) per 4 MB XCD L2, passes 2-5 L2-resident.
    const int b = blockIdx.x % NB;
    const int chunk = blockIdx.x / NB;

    __shared__ double sp[12];
    __shared__ double lds[TPB / 64][27];

    float R[9], t[3];
    if (it == 0) {
        R[0]=1.f; R[1]=0.f; R[2]=0.f;
        R[3]=0.f; R[4]=1.f; R[5]=0.f;
        R[6]=0.f; R[7]=0.f; R[8]=1.f;
        t[0]=t[1]=t[2]=0.f;
    } else {
        // wave 0 redundantly computes pose_it from pose_{it-1} + acc_{it-1}
        if ((threadIdx.x >> 6) == 0) {
            const double* accp = ws + ACC_OFF + ((size_t)(it-1) * NB + b) * 27;
            const double* pin  = ws + POSE_OFF + (size_t)((it-1) & 1) * NB * 12 + b * 12;
            double Rn[9], tn[3];
            solve_update(accp, pin, Rn, tn);
            if (threadIdx.x == 0) {
                #pragma unroll
                for (int i = 0; i < 9; i++) sp[i] = Rn[i];
                sp[9] = tn[0]; sp[10] = tn[1]; sp[11] = tn[2];
                if (chunk == 0) {   // single writer publishes pose_it (read next dispatch)
                    double* pout = ws + POSE_OFF + (size_t)(it & 1) * NB * 12 + b * 12;
                    #pragma unroll
                    for (int i = 0; i < 9; i++) pout[i] = Rn[i];
                    pout[9] = tn[0]; pout[10] = tn[1]; pout[11] = tn[2];
                }
            }
        }
        __syncthreads();
        #pragma unroll
        for (int i = 0; i < 9; i++) R[i] = (float)sp[i];
        t[0] = (float)sp[9]; t[1] = (float)sp[10]; t[2] = (float)sp[11];
    }

    const float fx = Kmat[b*9 + 0];
    const float fy = Kmat[b*9 + 4];
    const float cx = Kmat[b*9 + 2];
    const float cy = Kmat[b*9 + 5];
    const float delta = (float)(0.1 * sqrt(((double)(IMW*IMW - 1) + (double)(IMH*IMH - 1)) / 12.0));

    float facc[27];
    #pragma unroll
    for (int i = 0; i < 27; i++) facc[i] = 0.0f;

    // 4 consecutive points/thread, same pixel row (n0%4==0, IMW%4==0)
    const int ft = chunk * TPB + threadIdx.x;          // [0, 27648)
    const int n0 = ft * PPT;
    const int v0 = n0 / IMW;
    const float cyv  = cy - (float)v0;
    const float cxu0 = cx - (float)(n0 - v0 * IMW);

    const float4* P4 = reinterpret_cast<const float4*>(x3d + (size_t)b * NPIX * 3) + (size_t)ft * 3;
    const float4 va = P4[0];
    const float4 vb = P4[1];
    const float4 vc = P4[2];
    const float4 vw = reinterpret_cast<const float4*>(conf + (size_t)b * NPIX)[ft];

    float ppx[4] = { va.x, va.w, vb.z, vc.y };
    float ppy[4] = { va.y, vb.x, vb.w, vc.z };
    float ppz[4] = { va.z, vb.y, vc.x, vc.w };
    float pw[4]  = { vw.x, vw.y, vw.z, vw.w };

    #pragma unroll
    for (int g = 0; g < PPT; ++g) {
        float px = ppx[g], py = ppy[g], pz = ppz[g], w = pw[g];
        float u_off = cxu0 - (float)g;

        float Xx = fmaf(R[0], px, fmaf(R[1], py, fmaf(R[2], pz, t[0])));
        float Xy = fmaf(R[3], px, fmaf(R[4], py, fmaf(R[5], pz, t[1])));
        float Xz = fmaf(R[6], px, fmaf(R[7], py, fmaf(R[8], pz, t[2])));
        float z  = fmaxf(Xz, 0.01f);
        float iz = __builtin_amdgcn_rcpf(z);

        float Xxiz = Xx * iz, Xyiz = Xy * iz;
        float rx = fmaf(fx, Xxiz, u_off);
        float ry = fmaf(fy, Xyiz, cyv);

        float wrx = w * rx, wry = w * ry;
        float q  = fmaf(wrx, wrx, wry * wry);
        float rs = __builtin_amdgcn_rsqf(fmaxf(q, 1e-16f));
        float rob2 = fminf(1.0f, delta * rs);
        float sq = w * __builtin_amdgcn_sqrtf(rob2);

        float sqiz = sq * iz;
        float a  = fx * sqiz;
        float c  = fy * sqiz;
        float bb = -a * Xxiz;
        float d  = -c * Xyiz;

        float j0[6] = { a, 0.0f, bb,  bb*Xy,               fmaf(a, Xz, -bb*Xx), -a*Xy };
        float j1[6] = { 0.0f, c,  d,  fmaf(d, Xy, -c*Xz), -d*Xx,                 c*Xx };
        float rxs = sq * rx, rys = sq * ry;

        int k = 0;
        #pragma unroll
        for (int f = 0; f < 6; ++f) {
            #pragma unroll
            for (int gg = f; gg < 6; ++gg) {
                facc[k] += j0[f]*j0[gg] + j1[f]*j1[gg];
                k++;
            }
        }
        #pragma unroll
        for (int f = 0; f < 6; ++f)
            facc[21 + f] += j0[f]*rxs + j1[f]*rys;
    }

    // f32 wave reduce (pairwise), f64 from wave partials on
    int lane = threadIdx.x & 63;
    int wave = threadIdx.x >> 6;
    #pragma unroll
    for (int i = 0; i < 27; i++) {
        float v = facc[i];
        for (int off = 32; off > 0; off >>= 1) v += __shfl_down(v, off, 64);
        if (lane == 0) lds[wave][i] = (double)v;
    }
    __syncthreads();

    double* acc = ws + ACC_OFF + ((size_t)it * NB + b) * 27;
    if (threadIdx.x < 27) {
        double v = 0.0;
        #pragma unroll
        for (int wv = 0; wv < TPB/64; wv++) v += lds[wv][threadIdx.x];
        atomicAdd(acc + threadIdx.x, v);
    }
}

__global__ __launch_bounds__(64) void loss_k(const double* __restrict__ ws,
                                             const float* __restrict__ pose,
                                             float* __restrict__ out) {
    int lane = threadIdx.x;
    double Rp[9] = {1,0,0, 0,1,0, 0,0,1}, tp[3] = {0,0,0};
    if (lane < NB) {
        const double* accp = ws + ACC_OFF + ((size_t)(NITER-1) * NB + lane) * 27;
        const double* pin  = ws + POSE_OFF + (size_t)((NITER-1) & 1) * NB * 12 + lane * 12;
        solve_update(accp, pin, Rp, tp);
    }
    // broadcast batch-0 predicted pose to all lanes
    double Rp0[9], tp0v[3];
    #pragma unroll
    for (int i = 0; i < 9; i++) Rp0[i] = __shfl(Rp[i], 0, 64);
    #pragma unroll
    for (int i = 0; i < 3; i++) tp0v[i] = __shfl(tp[i], 0, 64);

    double rot = 0.0, trans = 0.0;
    if (lane < NB) {
        // gt_rel = inv(P0) @ Pb
        const float* P0 = pose;
        const float* Pb = pose + lane * 16;
        double R0t[9];
        #pragma unroll
        for (int i = 0; i < 3; i++)
            #pragma unroll
            for (int j = 0; j < 3; j++) R0t[i*3+j] = (double)P0[j*4+i];
        double t0i[3];
        #pragma unroll
        for (int i = 0; i < 3; i++)
            t0i[i] = -(R0t[i*3+0]*P0[0*4+3] + R0t[i*3+1]*P0[1*4+3] + R0t[i*3+2]*P0[2*4+3]);
        double Rg[9], tg[3];
        #pragma unroll
        for (int i = 0; i < 3; i++) {
            #pragma unroll
            for (int j = 0; j < 3; j++)
                Rg[i*3+j] = R0t[i*3+0]*Pb[0*4+j] + R0t[i*3+1]*Pb[1*4+j] + R0t[i*3+2]*Pb[2*4+j];
            tg[i] = R0t[i*3+0]*Pb[0*4+3] + R0t[i*3+1]*Pb[1*4+3] + R0t[i*3+2]*Pb[2*4+3] + t0i[i];
        }
        // pred_rel = inv(T0) @ Tb   (T0 from lane 0 broadcast)
        double Rp0t[9];
        #pragma unroll
        for (int i = 0; i < 3; i++)
            #pragma unroll
            for (int j = 0; j < 3; j++) Rp0t[i*3+j] = Rp0[j*3+i];
        double tp0i[3];
        #pragma unroll
        for (int i = 0; i < 3; i++)
            tp0i[i] = -(Rp0t[i*3+0]*tp0v[0] + Rp0t[i*3+1]*tp0v[1] + Rp0t[i*3+2]*tp0v[2]);
        double Rr[9], tr[3];
        #pragma unroll
        for (int i = 0; i < 3; i++) {
            #pragma unroll
            for (int j = 0; j < 3; j++)
                Rr[i*3+j] = Rp0t[i*3+0]*Rp[0*3+j] + Rp0t[i*3+1]*Rp[1*3+j] + Rp0t[i*3+2]*Rp[2*3+j];
            tr[i] = Rp0t[i*3+0]*tp[0] + Rp0t[i*3+1]*tp[1] + Rp0t[i*3+2]*tp[2] + tp0i[i];
        }
        double trace = 0.0;
        #pragma unroll
        for (int i = 0; i < 3; i++)
            trace += Rr[0*3+i]*Rg[0*3+i] + Rr[1*3+i]*Rg[1*3+i] + Rr[2*3+i]*Rg[2*3+i];
        double cosang = 0.5 * (trace - 1.0);
        cosang = fmin(fmax(cosang, -1.0 + 1e-7), 1.0 - 1e-7);
        rot = acos(cosang);
        double d0 = tr[0]-tg[0], d1 = tr[1]-tg[1], d2 = tr[2]-tg[2];
        trans = sqrt(d0*d0 + d1*d1 + d2*d2);
    }
    for (int off = 8; off > 0; off >>= 1) {
        rot   += __shfl_down(rot, off, 64);
        trans += __shfl_down(trans, off, 64);
    }
    if (lane == 0) {
        rot /= NB; trans /= NB;
        out[0] = (float)(rot + trans);
        out[1] = (float)rot;
        out[2] = (float)trans;
    }
}

extern "C" void kernel_launch(void* const* d_in, const int* in_sizes, int n_in,
                              void* d_out, int out_size, void* d_ws, size_t ws_size,
                              hipStream_t stream) {
    const float* x3d  = (const float*)d_in[0];
    const float* conf = (const float*)d_in[1];
    const float* Kmat = (const float*)d_in[2];
    const float* pose = (const float*)d_in[3];
    float* out = (float*)d_out;
    double* ws = (double*)d_ws;

    hipLaunchKernelGGL(init_k, dim3(1), dim3(TPB), 0, stream, ws);
    for (int it = 0; it < NITER; ++it) {
        hipLaunchKernelGGL(reduce_k, dim3(NBLK), dim3(TPB), 0, stream,
                           x3d, conf, Kmat, ws, it);
    }
    hipLaunchKernelGGL(loss_k, dim3(1), dim3(64), 0, stream, ws, pose, out);
}

// Round 10
// 86.244 us; speedup vs baseline: 2.2195x; 1.2654x over previous
//
#include <hip/hip_runtime.h>
#include <math.h>

#define NB 16
#define IMH 288
#define IMW 384
#define NPIX (IMH*IMW)
#define TPB 256
#define PPT 8
#define BPB (NPIX/(TPB*PPT))   // 54 blocks per batch
#define NBLK (NB*BPB)          // 864
#define NITER 5

// ws doubles layout: pose[2][NB][12] (R[9]+t[3], parity buffers) | acc[NITER][NB][27]
#define POSE_OFF 0
#define ACC_OFF (2*NB*12)
#define WS_DOUBLES (2*NB*12 + NITER*NB*27)

// f32 register-resident LM update (matches reference's f32 trajectory);
// t accumulates in f64 (state), everything else f32. Fully unrolled.
__device__ __forceinline__ void solve_updatef(const double* __restrict__ acc,
                                              const double* __restrict__ pin,
                                              float* __restrict__ Ro,
                                              double* __restrict__ to) {
    float A[6][6], rhs[6], inv[6];
    {
        int k = 0;
        #pragma unroll
        for (int f = 0; f < 6; f++) {
            #pragma unroll 6
            for (int g = f; g < 6; g++) {
                float v = (float)acc[k];
                A[f][g] = v; A[g][f] = v; k++;
            }
        }
    }
    #pragma unroll
    for (int f = 0; f < 6; f++) rhs[f] = -(float)acc[21 + f];

    float tr = A[0][0]+A[1][1]+A[2][2]+A[3][3]+A[4][4]+A[5][5];
    float damp = 1e-4f * tr * (1.0f/6.0f) + 1e-6f;
    #pragma unroll
    for (int f = 0; f < 6; f++) A[f][f] += damp;

    #pragma unroll
    for (int j = 0; j < 6; j++) {
        float s = A[j][j];
        #pragma unroll 6
        for (int m = 0; m < j; m++) s = fmaf(-A[j][m], A[j][m], s);
        float dd = __builtin_amdgcn_sqrtf(fmaxf(s, 1e-20f));
        A[j][j] = dd;
        inv[j] = __builtin_amdgcn_rcpf(dd);
        #pragma unroll 6
        for (int i = j + 1; i < 6; i++) {
            float s2 = A[i][j];
            #pragma unroll 6
            for (int m = 0; m < j; m++) s2 = fmaf(-A[i][m], A[j][m], s2);
            A[i][j] = s2 * inv[j];
        }
    }
    #pragma unroll
    for (int i = 0; i < 6; i++) {
        float s = rhs[i];
        #pragma unroll 6
        for (int m = 0; m < i; m++) s = fmaf(-A[i][m], rhs[m], s);
        rhs[i] = s * inv[i];
    }
    #pragma unroll
    for (int i = 5; i >= 0; i--) {
        float s = rhs[i];
        #pragma unroll 6
        for (int m = i + 1; m < 6; m++) s = fmaf(-A[m][i], rhs[m], s);
        rhs[i] = s * inv[i];
    }

    to[0] = pin[9]  + (double)rhs[0];
    to[1] = pin[10] + (double)rhs[1];
    to[2] = pin[11] + (double)rhs[2];

    float wx = rhs[3], wy = rhs[4], wz = rhs[5];
    float th = fmaxf(__builtin_amdgcn_sqrtf(fmaf(wx,wx,fmaf(wy,wy,wz*wz))), 1e-8f);
    float ith = __builtin_amdgcn_rcpf(th);
    float kx = wx*ith, ky = wy*ith, kz = wz*ith;
    float st, ctf;
    sincosf(th, &st, &ctf);
    float ct = 1.0f - ctf;
    float E[9];
    E[0] = 1.0f + ct*(kx*kx - 1.0f);
    E[1] = -st*kz + ct*kx*ky;
    E[2] =  st*ky + ct*kx*kz;
    E[3] =  st*kz + ct*ky*kx;
    E[4] = 1.0f + ct*(ky*ky - 1.0f);
    E[5] = -st*kx + ct*ky*kz;
    E[6] = -st*ky + ct*kz*kx;
    E[7] =  st*kx + ct*kz*ky;
    E[8] = 1.0f + ct*(kz*kz - 1.0f);

    float Rin[9];
    #pragma unroll
    for (int i = 0; i < 9; i++) Rin[i] = (float)pin[i];
    #pragma unroll
    for (int i = 0; i < 3; i++) {
        #pragma unroll
        for (int j = 0; j < 3; j++)
            Ro[i*3+j] = E[i*3+0]*Rin[0*3+j] + E[i*3+1]*Rin[1*3+j] + E[i*3+2]*Rin[2*3+j];
    }
}

__global__ void init_k(double* ws) {
    int i = threadIdx.x;
    for (int k = i; k < WS_DOUBLES; k += TPB) ws[k] = 0.0;
    __syncthreads();
    if (i < NB) {
        double* p = ws + POSE_OFF + i * 12;   // parity buffer 0 = identity
        p[0] = 1.0; p[4] = 1.0; p[8] = 1.0;
    }
}

__global__ __launch_bounds__(TPB) void reduce_k(const float* __restrict__ x3d,
                                                const float* __restrict__ conf,
                                                const float* __restrict__ Kmat,
                                                double* __restrict__ ws, int it) {
    const int b = blockIdx.x / BPB;
    const int chunk = blockIdx.x % BPB;
    const int tid = threadIdx.x;

    // ---- issue input loads FIRST (latency hides under prologue solve) ----
    const int ft = chunk * TPB + tid;              // [0, 13824)
    const float4* P4 = reinterpret_cast<const float4*>(x3d + (size_t)b * NPIX * 3) + (size_t)ft * 6;
    const float4* W4 = reinterpret_cast<const float4*>(conf + (size_t)b * NPIX) + (size_t)ft * 2;
    const float4 va = P4[0], vb = P4[1], vc = P4[2], vd = P4[3], ve = P4[4], vf = P4[5];
    const float4 w0 = W4[0], w1 = W4[1];

    __shared__ double lds[TPB / 64][27];

    // ---- per-wave redundant f32 pose solve: no barrier, no LDS broadcast ----
    float R[9], t[3];
    if (it == 0) {
        R[0]=1.f; R[1]=0.f; R[2]=0.f;
        R[3]=0.f; R[4]=1.f; R[5]=0.f;
        R[6]=0.f; R[7]=0.f; R[8]=1.f;
        t[0]=t[1]=t[2]=0.f;
    } else {
        float Rn[9]; double tn[3];
        solve_updatef(ws + ACC_OFF + ((size_t)(it-1) * NB + b) * 27,
                      ws + POSE_OFF + (size_t)((it-1) & 1) * NB * 12 + (size_t)b * 12,
                      Rn, tn);
        #pragma unroll
        for (int i = 0; i < 9; i++) R[i] = Rn[i];
        t[0] = (float)tn[0]; t[1] = (float)tn[1]; t[2] = (float)tn[2];
        if (chunk == 0 && tid == 0) {      // publish pose state for next dispatch
            double* pout = ws + POSE_OFF + (size_t)(it & 1) * NB * 12 + (size_t)b * 12;
            #pragma unroll
            for (int i = 0; i < 9; i++) pout[i] = (double)Rn[i];
            pout[9] = tn[0]; pout[10] = tn[1]; pout[11] = tn[2];
        }
    }

    const float fx = Kmat[b*9 + 0];
    const float fy = Kmat[b*9 + 4];
    const float cx = Kmat[b*9 + 2];
    const float cy = Kmat[b*9 + 5];
    const float delta = (float)(0.1 * sqrt(((double)(IMW*IMW - 1) + (double)(IMH*IMH - 1)) / 12.0));

    const int n0 = ft * PPT;
    const int v0 = n0 / IMW;                       // 8 points share one pixel row
    const float cyv  = cy - (float)v0;
    const float cxu0 = cx - (float)(n0 - v0 * IMW);

    float ppx[8] = { va.x, va.w, vb.z, vc.y, vd.x, vd.w, ve.z, vf.y };
    float ppy[8] = { va.y, vb.x, vb.w, vc.z, vd.y, ve.x, ve.w, vf.z };
    float ppz[8] = { va.z, vb.y, vc.x, vc.w, vd.z, ve.y, vf.x, vf.w };
    float pw[8]  = { w0.x, w0.y, w0.z, w0.w, w1.x, w1.y, w1.z, w1.w };

    float facc[27];
    #pragma unroll
    for (int i = 0; i < 27; i++) facc[i] = 0.0f;

    #pragma unroll
    for (int g = 0; g < PPT; ++g) {
        float px = ppx[g], py = ppy[g], pz = ppz[g], w = pw[g];
        float u_off = cxu0 - (float)g;

        float Xx = fmaf(R[0], px, fmaf(R[1], py, fmaf(R[2], pz, t[0])));
        float Xy = fmaf(R[3], px, fmaf(R[4], py, fmaf(R[5], pz, t[1])));
        float Xz = fmaf(R[6], px, fmaf(R[7], py, fmaf(R[8], pz, t[2])));
        float z  = fmaxf(Xz, 0.01f);
        float iz = __builtin_amdgcn_rcpf(z);

        float Xxiz = Xx * iz, Xyiz = Xy * iz;
        float rx = fmaf(fx, Xxiz, u_off);
        float ry = fmaf(fy, Xyiz, cyv);

        float wrx = w * rx, wry = w * ry;
        float q  = fmaf(wrx, wrx, wry * wry);
        float rs = __builtin_amdgcn_rsqf(fmaxf(q, 1e-16f));
        float rob2 = fminf(1.0f, delta * rs);
        float sq = w * __builtin_amdgcn_sqrtf(rob2);

        float sqiz = sq * iz;
        float a  = fx * sqiz;
        float c  = fy * sqiz;
        float bb = -a * Xxiz;
        float d  = -c * Xyiz;

        float j0[6] = { a, 0.0f, bb,  bb*Xy,               fmaf(a, Xz, -bb*Xx), -a*Xy };
        float j1[6] = { 0.0f, c,  d,  fmaf(d, Xy, -c*Xz), -d*Xx,                 c*Xx };
        float rxs = sq * rx, rys = sq * ry;

        int k = 0;
        #pragma unroll
        for (int f = 0; f < 6; ++f) {
            #pragma unroll
            for (int gg = f; gg < 6; ++gg) {
                facc[k] += j0[f]*j0[gg] + j1[f]*j1[gg];
                k++;
            }
        }
        #pragma unroll
        for (int f = 0; f < 6; ++f)
            facc[21 + f] += j0[f]*rxs + j1[f]*rys;
    }

    // f32 wave reduce (pairwise), f64 from wave partials on
    int lane = tid & 63;
    int wave = tid >> 6;
    #pragma unroll
    for (int i = 0; i < 27; i++) {
        float v = facc[i];
        for (int off = 32; off > 0; off >>= 1) v += __shfl_down(v, off, 64);
        if (lane == 0) lds[wave][i] = (double)v;
    }
    __syncthreads();

    double* acc = ws + ACC_OFF + ((size_t)it * NB + b) * 27;
    if (tid < 27) {
        double v = 0.0;
        #pragma unroll
        for (int wv = 0; wv < TPB/64; wv++) v += lds[wv][tid];
        atomicAdd(acc + tid, v);
    }
}

__global__ __launch_bounds__(64) void loss_k(const double* __restrict__ ws,
                                             const float* __restrict__ pose,
                                             float* __restrict__ out) {
    int lane = threadIdx.x;
    double Rp[9] = {1,0,0, 0,1,0, 0,0,1}, tp[3] = {0,0,0};
    if (lane < NB) {
        float Rn[9]; double tn[3];
        solve_updatef(ws + ACC_OFF + ((size_t)(NITER-1) * NB + lane) * 27,
                      ws + POSE_OFF + (size_t)((NITER-1) & 1) * NB * 12 + (size_t)lane * 12,
                      Rn, tn);
        #pragma unroll
        for (int i = 0; i < 9; i++) Rp[i] = (double)Rn[i];
        tp[0] = tn[0]; tp[1] = tn[1]; tp[2] = tn[2];
    }
    // broadcast batch-0 predicted pose to all lanes
    double Rp0[9], tp0v[3];
    #pragma unroll
    for (int i = 0; i < 9; i++) Rp0[i] = __shfl(Rp[i], 0, 64);
    #pragma unroll
    for (int i = 0; i < 3; i++) tp0v[i] = __shfl(tp[i], 0, 64);

    double rot = 0.0, trans = 0.0;
    if (lane < NB) {
        // gt_rel = inv(P0) @ Pb
        const float* P0 = pose;
        const float* Pb = pose + lane * 16;
        double R0t[9];
        #pragma unroll
        for (int i = 0; i < 3; i++)
            #pragma unroll
            for (int j = 0; j < 3; j++) R0t[i*3+j] = (double)P0[j*4+i];
        double t0i[3];
        #pragma unroll
        for (int i = 0; i < 3; i++)
            t0i[i] = -(R0t[i*3+0]*P0[0*4+3] + R0t[i*3+1]*P0[1*4+3] + R0t[i*3+2]*P0[2*4+3]);
        double Rg[9], tg[3];
        #pragma unroll
        for (int i = 0; i < 3; i++) {
            #pragma unroll
            for (int j = 0; j < 3; j++)
                Rg[i*3+j] = R0t[i*3+0]*Pb[0*4+j] + R0t[i*3+1]*Pb[1*4+j] + R0t[i*3+2]*Pb[2*4+j];
            tg[i] = R0t[i*3+0]*Pb[0*4+3] + R0t[i*3+1]*Pb[1*4+3] + R0t[i*3+2]*Pb[2*4+3] + t0i[i];
        }
        // pred_rel = inv(T0) @ Tb
        double Rp0t[9];
        #pragma unroll
        for (int i = 0; i < 3; i++)
            #pragma unroll
            for (int j = 0; j < 3; j++) Rp0t[i*3+j] = Rp0[j*3+i];
        double tp0i[3];
        #pragma unroll
        for (int i = 0; i < 3; i++)
            tp0i[i] = -(Rp0t[i*3+0]*tp0v[0] + Rp0t[i*3+1]*tp0v[1] + Rp0t[i*3+2]*tp0v[2]);
        double Rr[9], tr[3];
        #pragma unroll
        for (int i = 0; i < 3; i++) {
            #pragma unroll
            for (int j = 0; j < 3; j++)
                Rr[i*3+j] = Rp0t[i*3+0]*Rp[0*3+j] + Rp0t[i*3+1]*Rp[1*3+j] + Rp0t[i*3+2]*Rp[2*3+j];
            tr[i] = Rp0t[i*3+0]*tp[0] + Rp0t[i*3+1]*tp[1] + Rp0t[i*3+2]*tp[2] + tp0i[i];
        }
        double trace = 0.0;
        #pragma unroll
        for (int i = 0; i < 3; i++)
            trace += Rr[0*3+i]*Rg[0*3+i] + Rr[1*3+i]*Rg[1*3+i] + Rr[2*3+i]*Rg[2*3+i];
        double cosang = 0.5 * (trace - 1.0);
        cosang = fmin(fmax(cosang, -1.0 + 1e-7), 1.0 - 1e-7);
        rot = acos(cosang);
        double d0 = tr[0]-tg[0], d1 = tr[1]-tg[1], d2 = tr[2]-tg[2];
        trans = sqrt(d0*d0 + d1*d1 + d2*d2);
    }
    for (int off = 8; off > 0; off >>= 1) {
        rot   += __shfl_down(rot, off, 64);
        trans += __shfl_down(trans, off, 64);
    }
    if (lane == 0) {
        rot /= NB; trans /= NB;
        out[0] = (float)(rot + trans);
        out[1] = (float)rot;
        out[2] = (float)trans;
    }
}

extern "C" void kernel_launch(void* const* d_in, const int* in_sizes, int n_in,
                              void* d_out, int out_size, void* d_ws, size_t ws_size,
                              hipStream_t stream) {
    const float* x3d  = (const float*)d_in[0];
    const float* conf = (const float*)d_in[1];
    const float* Kmat = (const float*)d_in[2];
    const float* pose = (const float*)d_in[3];
    float* out = (float*)d_out;
    double* ws = (double*)d_ws;

    hipLaunchKernelGGL(init_k, dim3(1), dim3(TPB), 0, stream, ws);
    for (int it = 0; it < NITER; ++it) {
        hipLaunchKernelGGL(reduce_k, dim3(NBLK), dim3(TPB), 0, stream,
                           x3d, conf, Kmat, ws, it);
    }
    hipLaunchKernelGGL(loss_k, dim3(1), dim3(64), 0, stream, ws, pose, out);
}